// Round 10
// baseline (194.263 us; speedup 1.0000x reference)
//
#include <hip/hip_runtime.h>
#include <stdint.h>

// ---------------------------------------------------------------------------
// MultiHeadAttention forward, MI355X/gfx950.  Round 10.
// fp32 I/O, bf16 MFMA compute. B=2 S=2048 D=1024 H=16 HD=64. M=4096.
// R10 vs R9 (188.5 us; attn 60.3):
//  attn rebuilt: K/V staged via global_load_lds width=16 into DOUBLE-BUFFERED
//  LDS; prefetch(kt+1) issued right after the single per-iter barrier, so the
//  next barrier's vmcnt(0) drain comes after a full iter of compute (real
//  async overlap). Ps shrunk to a 32-key quarter (128x40, 16B-aligned rows)
//  so LDS = 32(Kx2) + 32(Vx2) + 10(Ps) = 74 KB -> 2 blocks/CU holds.
//  Per-wave-iter LDS bytes 56->48 KB; barriers/iter 2->1; staging VGPR
//  round-trip eliminated. GEMMs unchanged (m99/m131-140: gemm dbuf neutral).
// MFMA mfma_f32_16x16x32_bf16 layouts [m89-verified]:
//   A-frag: lane(quad,l15) holds A[m=l15][k=quad*8+j]  (contig bf16x8)
//   B-frag: B[n=l15][k=quad*8+j];  C/D: col=l15, row=quad*4+reg
// Async swizzles: K/Q rows (64-wide): LDS[r][pc]=G[r][pc^(r&7)];
//                 V  rows (128-wide): LDS[hd][pc]=G[hd][pc^(hd&15)].
// ---------------------------------------------------------------------------

typedef __bf16 bf16_t;
typedef __bf16 bf16x8 __attribute__((ext_vector_type(8)));
typedef float  f32x4  __attribute__((ext_vector_type(4)));
typedef uint32_t u32x4 __attribute__((ext_vector_type(4)));

#define MFMA16(A, B, C) __builtin_amdgcn_mfma_f32_16x16x32_bf16(A, B, C, 0, 0, 0)

__device__ __forceinline__ void async_ld16(const bf16_t* g, bf16_t* l) {
  __builtin_amdgcn_global_load_lds(
      (const __attribute__((address_space(1))) void*)g,
      (__attribute__((address_space(3))) void*)l, 16, 0, 0);
}

__device__ __forceinline__ u32x4 ld8(const float* p) {
  const float4 a = *(const float4*)p;
  const float4 b = *(const float4*)(p + 4);
  union { u32x4 v; bf16_t h[8]; } r;
  r.h[0] = (bf16_t)a.x; r.h[1] = (bf16_t)a.y;
  r.h[2] = (bf16_t)a.z; r.h[3] = (bf16_t)a.w;
  r.h[4] = (bf16_t)b.x; r.h[5] = (bf16_t)b.y;
  r.h[6] = (bf16_t)b.z; r.h[7] = (bf16_t)b.w;
  return r.v;
}

// --- fp32 -> bf16 converter: y=0 x (4096 blks); y=1..3 Wq/Wk/Wv (1024) -----
__global__ __launch_bounds__(256) void cvt_all(
    const float* __restrict__ sx, const float* __restrict__ s1,
    const float* __restrict__ s2, const float* __restrict__ s3,
    bf16_t* __restrict__ dx, bf16_t* __restrict__ d1,
    bf16_t* __restrict__ d2, bf16_t* __restrict__ d3) {
  const int y = blockIdx.y;
  if (y != 0 && blockIdx.x >= 1024) return;
  const int i4 = (blockIdx.x * 256 + threadIdx.x) * 4;
  const float* s = (y == 0) ? sx : (y == 1) ? s1 : (y == 2) ? s2 : s3;
  bf16_t*      d = (y == 0) ? dx : (y == 1) ? d1 : (y == 2) ? d2 : d3;
  const float4 v = *(const float4*)(s + i4);
  union { uint64_t u; bf16_t h[4]; } pk;
  pk.h[0] = (bf16_t)v.x; pk.h[1] = (bf16_t)v.y;
  pk.h[2] = (bf16_t)v.z; pk.h[3] = (bf16_t)v.w;
  *(uint64_t*)(d + i4) = pk.u;
}

// ---------------------------------------------------------------------------
// Async-staged bf16 GEMM (128x128, BK=64): QKV projections. (unchanged R9)
// ---------------------------------------------------------------------------
__global__ __launch_bounds__(256, 2) void gemm_qkv_a(
    const bf16_t* __restrict__ X,  const bf16_t* __restrict__ Wq,
    const bf16_t* __restrict__ Wk, const bf16_t* __restrict__ Wv,
    bf16_t* __restrict__ Q, bf16_t* __restrict__ K, bf16_t* __restrict__ V) {
  const int z = blockIdx.z;
  const bf16_t* W = (z == 0) ? Wq : (z == 1) ? Wk : Wv;
  bf16_t*       D = (z == 0) ? Q  : (z == 1) ? K  : V;
  const int mode = (z == 2) ? 1 : 0;

  __shared__ __align__(16) bf16_t As[128 * 64];
  __shared__ __align__(16) bf16_t Bs[128 * 64];

  const int tid  = threadIdx.x;
  const int lane = tid & 63;
  const int w    = tid >> 6;
  const int quad = lane >> 4;
  const int l15  = lane & 15;
  const int bm   = blockIdx.y * 128;
  const int bn   = blockIdx.x * 128;
  const int wm   = (w >> 1) * 64;
  const int wn   = (w & 1) * 64;
  const int sr   = lane >> 3;
  const int sc   = lane & 7;

  f32x4 acc[4][4] = {};

  for (int k0 = 0; k0 < 1024; k0 += 64) {
#pragma unroll
    for (int j = 0; j < 4; ++j) {
      const int r0 = w * 32 + j * 8;
      const int r  = r0 + sr;
      const int c  = sc ^ (r & 7);
      async_ld16(X + (size_t)(bm + r) * 1024 + k0 + c * 8, &As[r0 * 64]);
      async_ld16(W + (size_t)(bn + r) * 1024 + k0 + c * 8, &Bs[r0 * 64]);
    }
    __syncthreads();
#pragma unroll
    for (int kk = 0; kk < 64; kk += 32) {
      const int ck = (kk >> 3) + quad;
      bf16x8 aF[4], bF[4];
#pragma unroll
      for (int mt = 0; mt < 4; ++mt) {
        const int r = wm + mt * 16 + l15;
        aF[mt] = *(const bf16x8*)&As[r * 64 + (ck ^ (r & 7)) * 8];
      }
#pragma unroll
      for (int nt = 0; nt < 4; ++nt) {
        const int r = wn + nt * 16 + l15;
        bF[nt] = *(const bf16x8*)&Bs[r * 64 + (ck ^ (r & 7)) * 8];
      }
#pragma unroll
      for (int mt = 0; mt < 4; ++mt)
#pragma unroll
        for (int nt = 0; nt < 4; ++nt)
          acc[mt][nt] = MFMA16(aF[mt], bF[nt], acc[mt][nt]);
    }
    __syncthreads();
  }

#pragma unroll
  for (int mt = 0; mt < 4; ++mt) {
#pragma unroll
    for (int nt = 0; nt < 4; ++nt) {
      const int n  = bn + wn + nt * 16 + l15;
      const int mb = bm + wm + mt * 16 + quad * 4;
      const int h = n >> 6, hd = n & 63;
      if (mode == 0) {               // Q/K: [B,H,S,64]
#pragma unroll
        for (int r = 0; r < 4; ++r) {
          const int m = mb + r;
          const int b = m >> 11, s = m & 2047;
          D[(size_t)b * 2097152 + (size_t)h * 131072 + (size_t)s * 64 + hd] =
              (bf16_t)acc[mt][nt][r];
        }
      } else {                       // V^T: [B,H,64,S]; 4 consecutive tokens
        const int b = mb >> 11, s0 = mb & 2047;
        union { uint64_t u; bf16_t h4[4]; } pk;
#pragma unroll
        for (int r = 0; r < 4; ++r) pk.h4[r] = (bf16_t)acc[mt][nt][r];
        *(uint64_t*)(D + (size_t)b * 2097152 + (size_t)h * 131072 +
                     (size_t)hd * 2048 + s0) = pk.u;
      }
    }
  }
}

// ---------------------------------------------------------------------------
// gemm_out: 64x128 tile, grid (8,64)=512 blocks. (unchanged R9)
// ---------------------------------------------------------------------------
__global__ __launch_bounds__(256, 2) void gemm_out_m(
    const bf16_t* __restrict__ ctx, const float* __restrict__ Wo,
    float* __restrict__ out, const float* __restrict__ bo) {
  __shared__ __align__(16) bf16_t As[64 * 64];
  __shared__ __align__(16) bf16_t Bs[128 * 64];

  const int tid  = threadIdx.x;
  const int lane = tid & 63;
  const int w    = tid >> 6;
  const int quad = lane >> 4;
  const int l15  = lane & 15;
  const int bm   = blockIdx.y * 64;
  const int bn   = blockIdx.x * 128;
  const int wm   = (w >> 1) * 32;
  const int wn   = (w & 1) * 64;
  const int sr   = lane >> 3;
  const int sc   = lane & 7;
  const int srow = tid >> 3;
  const int schk = tid & 7;

  f32x4 acc[2][4] = {};

  for (int k0 = 0; k0 < 1024; k0 += 64) {
#pragma unroll
    for (int j = 0; j < 2; ++j) {
      const int r0 = w * 16 + j * 8;
      const int r  = r0 + sr;
      const int c  = sc ^ (r & 7);
      async_ld16(ctx + (size_t)(bm + r) * 1024 + k0 + c * 8, &As[r0 * 64]);
    }
    u32x4 rb[4];
#pragma unroll
    for (int s2 = 0; s2 < 4; ++s2) {
      const int r = srow + s2 * 32;
      rb[s2] = ld8(Wo + (size_t)(bn + r) * 1024 + k0 + schk * 8);
    }
#pragma unroll
    for (int s2 = 0; s2 < 4; ++s2) {
      const int r = srow + s2 * 32;
      *(u32x4*)&Bs[r * 64 + ((schk ^ (r & 7)) * 8)] = rb[s2];
    }
    __syncthreads();
#pragma unroll
    for (int kk = 0; kk < 64; kk += 32) {
      const int ck = (kk >> 3) + quad;
      bf16x8 aF[2], bF[4];
#pragma unroll
      for (int mt = 0; mt < 2; ++mt) {
        const int r = wm + mt * 16 + l15;
        aF[mt] = *(const bf16x8*)&As[r * 64 + (ck ^ (r & 7)) * 8];
      }
#pragma unroll
      for (int nt = 0; nt < 4; ++nt) {
        const int r = wn + nt * 16 + l15;
        bF[nt] = *(const bf16x8*)&Bs[r * 64 + (ck ^ (r & 7)) * 8];
      }
#pragma unroll
      for (int mt = 0; mt < 2; ++mt)
#pragma unroll
        for (int nt = 0; nt < 4; ++nt)
          acc[mt][nt] = MFMA16(aF[mt], bF[nt], acc[mt][nt]);
    }
    __syncthreads();
  }

#pragma unroll
  for (int mt = 0; mt < 2; ++mt) {
#pragma unroll
    for (int nt = 0; nt < 4; ++nt) {
      const int n  = bn + wn + nt * 16 + l15;
      const int mb = bm + wm + mt * 16 + quad * 4;
      const float bv = bo[n];
#pragma unroll
      for (int r = 0; r < 4; ++r)
        out[(size_t)(mb + r) * 1024 + n] = acc[mt][nt][r] + bv;
    }
  }
}

// ---------------------------------------------------------------------------
// Flash-style causal attention, async double-buffered K/V, 1 barrier/iter.
// Grid (16,16,2), 256 thr; qt remap z==0 -> x, z==1 -> 15-x (ids differ by
// 256 -> same CU, 2 blocks/CU).  Q,K: [B,H,S,64]; V^T: [B,H,64,S].
// LDS: Kb[2] 32K + Vb[2] 32K + Ps(128x40 quarter) 10K = 74 KB.
// iter kt: barrier (drains async(kt), prior-iter reads done);
//          issue async(kt+1) -> buf[kt&1]; compute from buf[(kt+1)&1].
// Softmax: full-row max/alpha in regs, then per-32-key chunk:
//          exp -> Ps write (b64) -> pF/vF b128 reads -> 8 PV MFMA.
// ---------------------------------------------------------------------------
__global__ __launch_bounds__(256, 2) void attn(
    const bf16_t* __restrict__ Qw, const bf16_t* __restrict__ Kw,
    const bf16_t* __restrict__ Vw, bf16_t* __restrict__ ctx) {
  __shared__ __align__(16) bf16_t Kb[2][128 * 64];
  __shared__ __align__(16) bf16_t Vb[2][64 * 128];
  __shared__ __align__(16) bf16_t Ps[128 * 40];   // 32-key chunk, 80B rows

  const int tid  = threadIdx.x;
  const int lane = tid & 63;
  const int w    = tid >> 6;
  const int quad = lane >> 4;
  const int l15  = lane & 15;
  const int b    = blockIdx.z;
  const int qt   = (b == 0) ? blockIdx.x : 15 - blockIdx.x;
  const int h    = blockIdx.y;
  const size_t bh = (size_t)(b * 16 + h) * (size_t)(2048 * 64);
  const bf16_t* Qh = Qw + bh;
  const bf16_t* Kh = Kw + bh;
  const bf16_t* Vh = Vw + bh;       // [64][2048]

  const int srow = tid >> 3, schk = tid & 7;

  // --- async K/V tile stager: tile kt -> buffer bi -------------------------
  auto stage_async = [&](int kt, int bi) {
#pragma unroll
    for (int j = 0; j < 4; ++j) {               // K: 128 rows x 64 hd
      const int r0 = w * 32 + j * 8;
      const int r  = r0 + (lane >> 3);
      const int c  = (lane & 7) ^ (r & 7);
      async_ld16(Kh + (size_t)(kt * 128 + r) * 64 + c * 8, &Kb[bi][r0 * 64]);
    }
#pragma unroll
    for (int j = 0; j < 4; ++j) {               // V^T: 64 rows x 128 keys
      const int r0 = w * 16 + j * 4;
      const int hd = r0 + quad;                 // hd&15 == (j*4+quad)
      const int c  = (lane & 15) ^ (hd & 15);
      async_ld16(Vh + (size_t)hd * 2048 + kt * 128 + c * 8, &Vb[bi][r0 * 128]);
    }
  };

  // --- prologue: async kt=0 -> buf1; Q staged via regs into Kb[0] ----------
  stage_async(0, 1);
  {
    u32x4 rq[4];
#pragma unroll
    for (int s2 = 0; s2 < 4; ++s2)
      rq[s2] = *(const u32x4*)(Qh + (size_t)(qt * 128 + srow + s2 * 32) * 64 + schk * 8);
#pragma unroll
    for (int s2 = 0; s2 < 4; ++s2) {
      const int r = srow + s2 * 32;
      *(u32x4*)&Kb[0][r * 64 + ((schk ^ (r & 7)) * 8)] = rq[s2];
    }
  }
  __syncthreads();     // drains async(0) [vmcnt] + Q ds_writes [lgkmcnt]
  bf16x8 qF[2][2];
#pragma unroll
  for (int kq = 0; kq < 2; ++kq)
#pragma unroll
    for (int k2 = 0; k2 < 2; ++k2) {
      const int r  = w * 32 + kq * 16 + l15;
      const int ck = k2 * 4 + quad;
      qF[kq][k2] = *(const bf16x8*)&Kb[0][r * 64 + ((ck ^ (r & 7)) * 8)];
    }

  f32x4 O[2][4] = {};
  float mrow[2] = {-1e30f, -1e30f};
  float lrow[2] = {0.f, 0.f};
  const float sc_log2 = 0.125f * 1.44269504088896340736f;  // 1/sqrt(64)*log2e

  for (int kt = 0; kt <= qt; ++kt) {
    __syncthreads();   // drains async(kt); all reads of write-target buf done
    if (kt < qt) stage_async(kt + 1, kt & 1);   // overlaps entire iteration
    const bf16_t* K_ = Kb[(kt + 1) & 1];
    const bf16_t* V_ = Vb[(kt + 1) & 1];

    // --- S^T = K Q^T : q=l15 (col), key=ntk*16+quad*4+r ---
    f32x4 St[2][8] = {};
#pragma unroll
    for (int ntk = 0; ntk < 8; ++ntk) {
      const int kr = ntk * 16 + l15;
#pragma unroll
      for (int k2 = 0; k2 < 2; ++k2) {
        const int ck = k2 * 4 + quad;
        const bf16x8 kF = *(const bf16x8*)&K_[kr * 64 + ((ck ^ (kr & 7)) * 8)];
#pragma unroll
        for (int kq = 0; kq < 2; ++kq)
          St[kq][ntk] = MFMA16(kF, qF[kq][k2], St[kq][ntk]);
      }
    }

    // --- diag mask only on the diagonal tile ---
    if (kt == qt) {
#pragma unroll
      for (int kq = 0; kq < 2; ++kq) {
        const int ql = w * 32 + kq * 16 + l15;
#pragma unroll
        for (int ntk = 0; ntk < 8; ++ntk)
#pragma unroll
          for (int r = 0; r < 4; ++r)
            if (ntk * 16 + quad * 4 + r > ql) St[kq][ntk][r] = -1e30f;
      }
    }

    // --- full-row max / alpha (register-local + 2 shuffles) ---
    float aq[2], mn[2], rs[2] = {0.f, 0.f};
#pragma unroll
    for (int kq = 0; kq < 2; ++kq) {
      float mx = -1e30f;
#pragma unroll
      for (int ntk = 0; ntk < 8; ++ntk)
#pragma unroll
        for (int r = 0; r < 4; ++r) mx = fmaxf(mx, St[kq][ntk][r]);
      mx = fmaxf(mx, __shfl_xor(mx, 16));
      mx = fmaxf(mx, __shfl_xor(mx, 32));
      mn[kq] = fmaxf(mrow[kq], mx);
      aq[kq] = exp2f((mrow[kq] - mn[kq]) * sc_log2);
      mrow[kq] = mn[kq];
    }
    // rescale O before accumulating this tile (broadcast to O layout)
#pragma unroll
    for (int mt = 0; mt < 2; ++mt) {
#pragma unroll
      for (int r = 0; r < 4; ++r) {
        const float a = __shfl(aq[mt], quad * 4 + r);
#pragma unroll
        for (int nt = 0; nt < 4; ++nt) O[mt][nt][r] *= a;
      }
    }

    // --- per-32-key chunk: exp -> Ps -> PV MFMA ---
#pragma unroll
    for (int c = 0; c < 4; ++c) {
#pragma unroll
      for (int kq = 0; kq < 2; ++kq) {
        const int q = w * 32 + kq * 16 + l15;
#pragma unroll
        for (int t = 0; t < 2; ++t) {
          const int ntk = c * 2 + t;
          union { uint64_t u; bf16_t h4[4]; } pk;
#pragma unroll
          for (int r = 0; r < 4; ++r) {
            const float p = exp2f((St[kq][ntk][r] - mn[kq]) * sc_log2);
            rs[kq] += p;
            pk.h4[r] = (bf16_t)p;
          }
          *(uint64_t*)&Ps[q * 40 + t * 16 + quad * 4] = pk.u;
        }
      }
      // PV for this chunk (wave-private Ps rows; same-wave RAW, no barrier)
      bf16x8 pF[2], vF[4];
#pragma unroll
      for (int mt = 0; mt < 2; ++mt)
        pF[mt] = *(const bf16x8*)&Ps[(w * 32 + mt * 16 + l15) * 40 + quad * 8];
#pragma unroll
      for (int nt = 0; nt < 4; ++nt) {
        const int hd = nt * 16 + l15;
        const int lc = c * 4 + quad;
        vF[nt] = *(const bf16x8*)&V_[hd * 128 + ((lc ^ (hd & 15)) * 8)];
      }
#pragma unroll
      for (int mt = 0; mt < 2; ++mt)
#pragma unroll
        for (int nt = 0; nt < 4; ++nt)
          O[mt][nt] = MFMA16(pF[mt], vF[nt], O[mt][nt]);
    }

    // --- l update ---
#pragma unroll
    for (int kq = 0; kq < 2; ++kq) {
      float r = rs[kq];
      r += __shfl_xor(r, 16);
      r += __shfl_xor(r, 32);
      lrow[kq] = lrow[kq] * aq[kq] + r;
    }
  }

  // --- epilogue: normalize (lrow broadcast from q-column lanes), store ---
#pragma unroll
  for (int mt = 0; mt < 2; ++mt) {
#pragma unroll
    for (int r = 0; r < 4; ++r) {
      const float lr = __shfl(lrow[mt], quad * 4 + r);
      const float iv = 1.f / lr;
      const int s = qt * 128 + w * 32 + mt * 16 + quad * 4 + r;
#pragma unroll
      for (int nt = 0; nt < 4; ++nt) {
        const int hd = nt * 16 + l15;
        ctx[(size_t)(b * 2048 + s) * 1024 + h * 64 + hd] =
            (bf16_t)(O[mt][nt][r] * iv);
      }
    }
  }
}

// ---------------------------------------------------------------------------
extern "C" void kernel_launch(void* const* d_in, const int* in_sizes, int n_in,
                              void* d_out, int out_size, void* d_ws, size_t ws_size,
                              hipStream_t stream) {
  const float* x  = (const float*)d_in[0];
  const float* Wq = (const float*)d_in[1];
  const float* Wk = (const float*)d_in[2];
  const float* Wv = (const float*)d_in[3];
  const float* Wo = (const float*)d_in[4];
  const float* bo = (const float*)d_in[5];

  bf16_t* ws   = (bf16_t*)d_ws;       // ws: exactly 32 MB used
  bf16_t* Qw   = ws;                  // 4M bf16 elems each
  bf16_t* Kw   = ws + 4194304;
  bf16_t* Vw   = ws + 8388608;        // [B,H,64,S]
  bf16_t* ctxw = ws + 12582912;

  bf16_t* dscr = (bf16_t*)d_out;      // d_out as bf16 scratch (14 of 16 MB)
  bf16_t* xb   = dscr;                // 8 MB
  bf16_t* Wqb  = dscr + 4194304;      // 2 MB each
  bf16_t* Wkb  = dscr + 5242880;
  bf16_t* Wvb  = dscr + 6291456;      // ends at 14 MB
  float*  out  = (float*)d_out;       // final fp32 output overwrites scratch

  dim3 blk(256);
  cvt_all<<<dim3(4096, 4), blk, 0, stream>>>(x, Wq, Wk, Wv, xb, Wqb, Wkb, Wvb);
  gemm_qkv_a<<<dim3(8, 32, 3), blk, 0, stream>>>(xb, Wqb, Wkb, Wvb, Qw, Kw, Vw);
  attn<<<dim3(16, 16, 2), blk, 0, stream>>>(Qw, Kw, Vw, ctxw);
  gemm_out_m<<<dim3(8, 64), blk, 0, stream>>>(ctxw, Wo, out, bo);
}